// Round 1
// baseline (176.330 us; speedup 1.0000x reference)
//
#include <hip/hip_runtime.h>
#include <hip/hip_bf16.h>

#define TT 2048
#define CC 1024
#define DD 128
#define BB 8

typedef __attribute__((ext_vector_type(8))) short bf16x8;
typedef __attribute__((ext_vector_type(4))) float f32x4;
typedef __attribute__((ext_vector_type(4))) short short4v;

__device__ inline short f2bf(float f) {
    union { float f; unsigned u; } v; v.f = f;
    unsigned r = v.u + 0x7FFFu + ((v.u >> 16) & 1u);   // RNE
    return (short)(r >> 16);
}

// ---------------- Kernel 1: pack Wq|Wk|Wv -> bf16 Wall[384][1024] ----------------
__global__ void prep_w(const float* __restrict__ Wq, const float* __restrict__ Wk,
                       const float* __restrict__ Wv, short* __restrict__ Wall) {
    int row = blockIdx.x;  // 0..383
    const float* src = row < 128 ? Wq + (size_t)row * CC
                     : row < 256 ? Wk + (size_t)(row - 128) * CC
                                 : Wv + (size_t)(row - 256) * CC;
    short* dst = Wall + (size_t)row * CC;
    for (int j = threadIdx.x; j < CC; j += 256) dst[j] = f2bf(src[j]);
}

// ---------------- Kernel 2: QKV projection GEMM ----------------
// C[16384][384] = X[16384][1024] * Wall^T.  Block: 64 rows x 384 cols, 8 waves (2x4),
// each wave 32x96 via 2x6 16x16x32 MFMAs. Q,K stored [b][t][128] bf16; V stored
// transposed [b][128][2048] bf16.
__global__ __launch_bounds__(512) void qkv_gemm(const float* __restrict__ X,
                                                const short* __restrict__ Wall,
                                                short* __restrict__ Q,
                                                short* __restrict__ K,
                                                short* __restrict__ Vt) {
    int tid = threadIdx.x, lane = tid & 63, wid = tid >> 6;
    int wm = wid >> 2, wn = wid & 3;          // 2 x 4 wave grid
    int m0 = blockIdx.x * 64 + wm * 32;
    int n0 = wn * 96;
    int lg = lane >> 4, lr = lane & 15;

    f32x4 acc[2][6] = {};

    for (int kb = 0; kb < CC; kb += 32) {
        int kf = kb + lg * 8;
        bf16x8 a[2], bfr[6];
#pragma unroll
        for (int mi = 0; mi < 2; ++mi) {
            const float* p = X + (size_t)(m0 + mi * 16 + lr) * CC + kf;
            float4 f0 = *(const float4*)(p);
            float4 f1 = *(const float4*)(p + 4);
            bf16x8 t;
            t[0] = f2bf(f0.x); t[1] = f2bf(f0.y); t[2] = f2bf(f0.z); t[3] = f2bf(f0.w);
            t[4] = f2bf(f1.x); t[5] = f2bf(f1.y); t[6] = f2bf(f1.z); t[7] = f2bf(f1.w);
            a[mi] = t;
        }
#pragma unroll
        for (int nj = 0; nj < 6; ++nj) {
            const short* p = Wall + (size_t)(n0 + nj * 16 + lr) * CC + kf;
            bfr[nj] = *(const bf16x8*)(p);
        }
#pragma unroll
        for (int mi = 0; mi < 2; ++mi)
#pragma unroll
            for (int nj = 0; nj < 6; ++nj)
                acc[mi][nj] = __builtin_amdgcn_mfma_f32_16x16x32_bf16(a[mi], bfr[nj], acc[mi][nj], 0, 0, 0);
    }

    int bidx = (blockIdx.x * 64) / TT;   // 64 | 2048, block never straddles batches
#pragma unroll
    for (int mi = 0; mi < 2; ++mi) {
        int row = m0 + mi * 16 + lg * 4;          // global row for reg r=0
        int t = row - bidx * TT;
#pragma unroll
        for (int nj = 0; nj < 6; ++nj) {
            int col = n0 + nj * 16 + lr;          // frag base mult of 16 -> uniform branch
            if (col < 128) {
                short* dst = Q + ((size_t)bidx * TT + t) * DD + col;
#pragma unroll
                for (int r = 0; r < 4; ++r) dst[(size_t)r * DD] = f2bf(acc[mi][nj][r]);
            } else if (col < 256) {
                short* dst = K + ((size_t)bidx * TT + t) * DD + (col - 128);
#pragma unroll
                for (int r = 0; r < 4; ++r) dst[(size_t)r * DD] = f2bf(acc[mi][nj][r]);
            } else {
                short4v v4;
#pragma unroll
                for (int r = 0; r < 4; ++r) v4[r] = f2bf(acc[mi][nj][r]);
                *(short4v*)(Vt + ((size_t)bidx * DD + (col - 256)) * TT + t) = v4;
            }
        }
    }
}

// ---------------- Kernel 3: causal flash attention ----------------
// 1 wave per 16 query rows. 32-key tiles: S=Q*K^T (8 MFMAs), online softmax in fp32,
// P -> LDS -> A-frag, O += P*V via Vt (8 MFMAs). Output fp32 [b][t][128].
__global__ __launch_bounds__(64) void attn(const short* __restrict__ Q,
                                           const short* __restrict__ K,
                                           const short* __restrict__ Vt,
                                           float* __restrict__ out) {
    __shared__ short P[16 * 32];
    int lane = threadIdx.x;
    int lg = lane >> 4, lr = lane & 15;
    int gid = blockIdx.x;
    int b = gid & 7;
    int qt = 127 - (gid >> 3);        // heavy (high r0) tiles dispatched first
    int r0 = qt * 16;

    const short* Qb = Q + (size_t)b * TT * DD;
    const short* Kb = K + (size_t)b * TT * DD;
    const short* Vb = Vt + (size_t)b * DD * TT;

    bf16x8 qf[4];
#pragma unroll
    for (int c = 0; c < 4; ++c)
        qf[c] = *(const bf16x8*)(Qb + (size_t)(r0 + lr) * DD + c * 32 + lg * 8);

    f32x4 o[8] = {};
    float m[4], l[4];
#pragma unroll
    for (int r = 0; r < 4; ++r) { m[r] = -INFINITY; l[r] = 0.f; }

    const float scale = 0.08838834764831845f;  // 128^-0.5
    int ntiles = (r0 + 47) >> 5;               // ceil((r0+16)/32)

    for (int kt = 0; kt < ntiles; ++kt) {
        int kbase = kt * 32;
        f32x4 s[2] = {};
#pragma unroll
        for (int h = 0; h < 2; ++h)
#pragma unroll
            for (int c = 0; c < 4; ++c) {
                bf16x8 kf = *(const bf16x8*)(Kb + (size_t)(kbase + h * 16 + lr) * DD + c * 32 + lg * 8);
                s[h] = __builtin_amdgcn_mfma_f32_16x16x32_bf16(qf[c], kf, s[h], 0, 0, 0);
            }
#pragma unroll
        for (int h = 0; h < 2; ++h)
#pragma unroll
            for (int r = 0; r < 4; ++r) s[h][r] *= scale;

        if (kbase + 31 > r0) {  // causal mask needed only near the diagonal
#pragma unroll
            for (int h = 0; h < 2; ++h) {
                int key = kbase + h * 16 + lr;
#pragma unroll
                for (int r = 0; r < 4; ++r) {
                    int qrow = r0 + lg * 4 + r;
                    if (key > qrow) s[h][r] = -INFINITY;
                }
            }
        }

        // row max over the 16 lanes sharing this lane-group
        f32x4 tm;
#pragma unroll
        for (int r = 0; r < 4; ++r) tm[r] = fmaxf(s[0][r], s[1][r]);
#pragma unroll
        for (int off = 1; off < 16; off <<= 1)
#pragma unroll
            for (int r = 0; r < 4; ++r) tm[r] = fmaxf(tm[r], __shfl_xor(tm[r], off, 64));

        float sc[4], mn[4];
#pragma unroll
        for (int r = 0; r < 4; ++r) {
            mn[r] = fmaxf(m[r], tm[r]);
            sc[r] = __expf(m[r] - mn[r]);   // first tile: exp(-inf - finite) = 0
            m[r] = mn[r];
        }

        f32x4 p[2];
#pragma unroll
        for (int h = 0; h < 2; ++h)
#pragma unroll
            for (int r = 0; r < 4; ++r) p[h][r] = __expf(s[h][r] - mn[r]);  // masked -> 0

        f32x4 rs;
#pragma unroll
        for (int r = 0; r < 4; ++r) rs[r] = p[0][r] + p[1][r];
#pragma unroll
        for (int off = 1; off < 16; off <<= 1)
#pragma unroll
            for (int r = 0; r < 4; ++r) rs[r] += __shfl_xor(rs[r], off, 64);
#pragma unroll
        for (int r = 0; r < 4; ++r) l[r] = l[r] * sc[r] + rs[r];

#pragma unroll
        for (int dt = 0; dt < 8; ++dt)
#pragma unroll
            for (int r = 0; r < 4; ++r) o[dt][r] *= sc[r];

        __syncthreads();   // previous iteration's P reads are done
#pragma unroll
        for (int h = 0; h < 2; ++h)
#pragma unroll
            for (int r = 0; r < 4; ++r)
                P[(lg * 4 + r) * 32 + h * 16 + lr] = f2bf(p[h][r]);
        __syncthreads();   // P visible

        bf16x8 pa = *(const bf16x8*)(P + lr * 32 + lg * 8);  // A-frag of P

#pragma unroll
        for (int dt = 0; dt < 8; ++dt) {
            bf16x8 vf = *(const bf16x8*)(Vb + (size_t)(dt * 16 + lr) * TT + kbase + lg * 8);
            o[dt] = __builtin_amdgcn_mfma_f32_16x16x32_bf16(pa, vf, o[dt], 0, 0, 0);
        }
    }

    float* ob = out + ((size_t)b * TT + r0) * DD;
#pragma unroll
    for (int dt = 0; dt < 8; ++dt)
#pragma unroll
        for (int r = 0; r < 4; ++r)
            ob[(size_t)(lg * 4 + r) * DD + dt * 16 + lr] = o[dt][r] / l[r];
}

extern "C" void kernel_launch(void* const* d_in, const int* in_sizes, int n_in,
                              void* d_out, int out_size, void* d_ws, size_t ws_size,
                              hipStream_t stream) {
    const float* x  = (const float*)d_in[0];
    const float* Wq = (const float*)d_in[1];
    const float* Wk = (const float*)d_in[2];
    const float* Wv = (const float*)d_in[3];
    float* out = (float*)d_out;

    char* ws = (char*)d_ws;
    short* Wall = (short*)ws;                              // 384*1024*2   =  786,432 B
    short* Q    = (short*)(ws + 786432);                   // 8*2048*128*2 = 4,194,304 B
    short* K    = (short*)(ws + 786432 + 4194304);
    short* Vt   = (short*)(ws + 786432 + 2 * 4194304);     // total ~12.75 MB

    prep_w<<<384, 256, 0, stream>>>(Wq, Wk, Wv, Wall);
    qkv_gemm<<<16384 / 64, 512, 0, stream>>>(x, Wall, Q, K, Vt);
    attn<<<BB * 128, 64, 0, stream>>>(Q, K, Vt, out);
}

// Round 2
// 153.984 us; speedup vs baseline: 1.1451x; 1.1451x over previous
//
#include <hip/hip_runtime.h>
#include <hip/hip_bf16.h>

#define TT 2048
#define CC 1024
#define DD 128
#define BB 8

typedef __attribute__((ext_vector_type(8))) short bf16x8;
typedef __attribute__((ext_vector_type(4))) float f32x4;
typedef __attribute__((ext_vector_type(4))) short short4v;

__device__ inline short f2bf(float f) {
    union { float f; unsigned u; } v; v.f = f;
    unsigned r = v.u + 0x7FFFu + ((v.u >> 16) & 1u);   // RNE
    return (short)(r >> 16);
}

// ---------------- Kernel 1: pack Wq|Wk|Wv -> bf16 Wall[384][1024] ----------------
__global__ void prep_w(const float* __restrict__ Wq, const float* __restrict__ Wk,
                       const float* __restrict__ Wv, short* __restrict__ Wall) {
    int row = blockIdx.x;  // 0..383
    const float* src = row < 128 ? Wq + (size_t)row * CC
                     : row < 256 ? Wk + (size_t)(row - 128) * CC
                                 : Wv + (size_t)(row - 256) * CC;
    short* dst = Wall + (size_t)row * CC;
    for (int j = threadIdx.x; j < CC; j += 256) dst[j] = f2bf(src[j]);
}

// ---------------- Kernel 1b: X fp32 -> bf16, streaming ----------------
__global__ __launch_bounds__(256) void xconv(const float* __restrict__ X, short* __restrict__ Xb) {
    size_t i = ((size_t)blockIdx.x * 256 + threadIdx.x) * 8;   // grid covers n/8 exactly
    float4 f0 = *(const float4*)(X + i);
    float4 f1 = *(const float4*)(X + i + 4);
    bf16x8 t;
    t[0] = f2bf(f0.x); t[1] = f2bf(f0.y); t[2] = f2bf(f0.z); t[3] = f2bf(f0.w);
    t[4] = f2bf(f1.x); t[5] = f2bf(f1.y); t[6] = f2bf(f1.z); t[7] = f2bf(f1.w);
    *(bf16x8*)(Xb + i) = t;
}

// ---------------- Kernel 2a: QKV projection GEMM from bf16 X ----------------
// C[16384][384] = Xb[16384][1024] * Wall^T. Block: 64 rows x 384 cols, 8 waves (2x4).
__global__ __launch_bounds__(512) void qkv_gemm_bf(const short* __restrict__ Xb,
                                                   const short* __restrict__ Wall,
                                                   short* __restrict__ Q,
                                                   short* __restrict__ K,
                                                   short* __restrict__ Vt) {
    int tid = threadIdx.x, lane = tid & 63, wid = tid >> 6;
    int wm = wid >> 2, wn = wid & 3;
    int m0 = blockIdx.x * 64 + wm * 32;
    int n0 = wn * 96;
    int lg = lane >> 4, lr = lane & 15;

    f32x4 acc[2][6] = {};

    for (int kb = 0; kb < CC; kb += 32) {
        int kf = kb + lg * 8;
        bf16x8 a[2], bfr[6];
#pragma unroll
        for (int mi = 0; mi < 2; ++mi)
            a[mi] = *(const bf16x8*)(Xb + (size_t)(m0 + mi * 16 + lr) * CC + kf);
#pragma unroll
        for (int nj = 0; nj < 6; ++nj)
            bfr[nj] = *(const bf16x8*)(Wall + (size_t)(n0 + nj * 16 + lr) * CC + kf);
#pragma unroll
        for (int mi = 0; mi < 2; ++mi)
#pragma unroll
            for (int nj = 0; nj < 6; ++nj)
                acc[mi][nj] = __builtin_amdgcn_mfma_f32_16x16x32_bf16(a[mi], bfr[nj], acc[mi][nj], 0, 0, 0);
    }

    int bidx = (blockIdx.x * 64) / TT;
#pragma unroll
    for (int mi = 0; mi < 2; ++mi) {
        int row = m0 + mi * 16 + lg * 4;
        int t = row - bidx * TT;
#pragma unroll
        for (int nj = 0; nj < 6; ++nj) {
            int col = n0 + nj * 16 + lr;
            if (col < 128) {
                short* dst = Q + ((size_t)bidx * TT + t) * DD + col;
#pragma unroll
                for (int r = 0; r < 4; ++r) dst[(size_t)r * DD] = f2bf(acc[mi][nj][r]);
            } else if (col < 256) {
                short* dst = K + ((size_t)bidx * TT + t) * DD + (col - 128);
#pragma unroll
                for (int r = 0; r < 4; ++r) dst[(size_t)r * DD] = f2bf(acc[mi][nj][r]);
            } else {
                short4v v4;
#pragma unroll
                for (int r = 0; r < 4; ++r) v4[r] = f2bf(acc[mi][nj][r]);
                *(short4v*)(Vt + ((size_t)bidx * DD + (col - 256)) * TT + t) = v4;
            }
        }
    }
}

// ---------------- Kernel 2b: fallback (fp32 X loads), used if ws too small ----------------
__global__ __launch_bounds__(512) void qkv_gemm(const float* __restrict__ X,
                                                const short* __restrict__ Wall,
                                                short* __restrict__ Q,
                                                short* __restrict__ K,
                                                short* __restrict__ Vt) {
    int tid = threadIdx.x, lane = tid & 63, wid = tid >> 6;
    int wm = wid >> 2, wn = wid & 3;
    int m0 = blockIdx.x * 64 + wm * 32;
    int n0 = wn * 96;
    int lg = lane >> 4, lr = lane & 15;

    f32x4 acc[2][6] = {};

    for (int kb = 0; kb < CC; kb += 32) {
        int kf = kb + lg * 8;
        bf16x8 a[2], bfr[6];
#pragma unroll
        for (int mi = 0; mi < 2; ++mi) {
            const float* p = X + (size_t)(m0 + mi * 16 + lr) * CC + kf;
            float4 f0 = *(const float4*)(p);
            float4 f1 = *(const float4*)(p + 4);
            bf16x8 t;
            t[0] = f2bf(f0.x); t[1] = f2bf(f0.y); t[2] = f2bf(f0.z); t[3] = f2bf(f0.w);
            t[4] = f2bf(f1.x); t[5] = f2bf(f1.y); t[6] = f2bf(f1.z); t[7] = f2bf(f1.w);
            a[mi] = t;
        }
#pragma unroll
        for (int nj = 0; nj < 6; ++nj)
            bfr[nj] = *(const bf16x8*)(Wall + (size_t)(n0 + nj * 16 + lr) * CC + kf);
#pragma unroll
        for (int mi = 0; mi < 2; ++mi)
#pragma unroll
            for (int nj = 0; nj < 6; ++nj)
                acc[mi][nj] = __builtin_amdgcn_mfma_f32_16x16x32_bf16(a[mi], bfr[nj], acc[mi][nj], 0, 0, 0);
    }

    int bidx = (blockIdx.x * 64) / TT;
#pragma unroll
    for (int mi = 0; mi < 2; ++mi) {
        int row = m0 + mi * 16 + lg * 4;
        int t = row - bidx * TT;
#pragma unroll
        for (int nj = 0; nj < 6; ++nj) {
            int col = n0 + nj * 16 + lr;
            if (col < 128) {
                short* dst = Q + ((size_t)bidx * TT + t) * DD + col;
#pragma unroll
                for (int r = 0; r < 4; ++r) dst[(size_t)r * DD] = f2bf(acc[mi][nj][r]);
            } else if (col < 256) {
                short* dst = K + ((size_t)bidx * TT + t) * DD + (col - 128);
#pragma unroll
                for (int r = 0; r < 4; ++r) dst[(size_t)r * DD] = f2bf(acc[mi][nj][r]);
            } else {
                short4v v4;
#pragma unroll
                for (int r = 0; r < 4; ++r) v4[r] = f2bf(acc[mi][nj][r]);
                *(short4v*)(Vt + ((size_t)bidx * DD + (col - 256)) * TT + t) = v4;
            }
        }
    }
}

// ---------------- Kernel 3: causal flash attention, 8 waves / q-tile ----------------
// Block = 512 threads = 8 waves sharing one 16-row q-tile. Key tiles (32 keys) dealt
// cyclically to waves; each wave keeps private (m,l,O); block-level LDS combine.
__global__ __launch_bounds__(512) void attn(const short* __restrict__ Q,
                                            const short* __restrict__ K,
                                            const short* __restrict__ Vt,
                                            float* __restrict__ out) {
    __shared__ float Opart[8][16][132];     // padded (+4) to break lg-stride bank conflicts
    __shared__ float Mp[8][16], Lp[8][16], Esc[8][16], Lfin[16];
    __shared__ short Pbuf[8][512];          // per-wave P transpose buffer (no barriers)

    int tid = threadIdx.x;
    int lane = tid & 63, w = tid >> 6;
    int lg = lane >> 4, lr = lane & 15;
    int gid = blockIdx.x;
    int b = gid & 7;
    int qt = 127 - (gid >> 3);              // heavy tiles first
    int r0 = qt * 16;

    const short* Qb = Q + (size_t)b * TT * DD;
    const short* Kb = K + (size_t)b * TT * DD;
    const short* Vb = Vt + (size_t)b * DD * TT;

    bf16x8 qf[4];
#pragma unroll
    for (int c = 0; c < 4; ++c)
        qf[c] = *(const bf16x8*)(Qb + (size_t)(r0 + lr) * DD + c * 32 + lg * 8);

    f32x4 o[8] = {};
    float m[4], l[4];
#pragma unroll
    for (int r = 0; r < 4; ++r) { m[r] = -INFINITY; l[r] = 0.f; }

    const float scale = 0.08838834764831845f;  // 128^-0.5
    int ntiles = (r0 + 47) >> 5;               // ceil((r0+16)/32)

    for (int kt = w; kt < ntiles; kt += 8) {
        int kbase = kt * 32;
        f32x4 s[2] = {};
#pragma unroll
        for (int h = 0; h < 2; ++h)
#pragma unroll
            for (int c = 0; c < 4; ++c) {
                bf16x8 kf = *(const bf16x8*)(Kb + (size_t)(kbase + h * 16 + lr) * DD + c * 32 + lg * 8);
                s[h] = __builtin_amdgcn_mfma_f32_16x16x32_bf16(qf[c], kf, s[h], 0, 0, 0);
            }
#pragma unroll
        for (int h = 0; h < 2; ++h)
#pragma unroll
            for (int r = 0; r < 4; ++r) s[h][r] *= scale;

        if (kbase + 31 > r0) {
#pragma unroll
            for (int h = 0; h < 2; ++h) {
                int key = kbase + h * 16 + lr;
#pragma unroll
                for (int r = 0; r < 4; ++r) {
                    int qrow = r0 + lg * 4 + r;
                    if (key > qrow) s[h][r] = -INFINITY;
                }
            }
        }

        f32x4 tm;
#pragma unroll
        for (int r = 0; r < 4; ++r) tm[r] = fmaxf(s[0][r], s[1][r]);
#pragma unroll
        for (int off = 1; off < 16; off <<= 1)
#pragma unroll
            for (int r = 0; r < 4; ++r) tm[r] = fmaxf(tm[r], __shfl_xor(tm[r], off, 64));

        float sc[4], mm[4];
#pragma unroll
        for (int r = 0; r < 4; ++r) {
            float mn = fmaxf(m[r], tm[r]);
            mm[r] = (mn == -INFINITY) ? 0.f : mn;   // tile may be fully masked for low rows
            sc[r] = __expf(m[r] - mm[r]);
            m[r] = mn;
        }

        f32x4 p[2];
#pragma unroll
        for (int h = 0; h < 2; ++h)
#pragma unroll
            for (int r = 0; r < 4; ++r) p[h][r] = __expf(s[h][r] - mm[r]);

        f32x4 rs;
#pragma unroll
        for (int r = 0; r < 4; ++r) rs[r] = p[0][r] + p[1][r];
#pragma unroll
        for (int off = 1; off < 16; off <<= 1)
#pragma unroll
            for (int r = 0; r < 4; ++r) rs[r] += __shfl_xor(rs[r], off, 64);
#pragma unroll
        for (int r = 0; r < 4; ++r) l[r] = l[r] * sc[r] + rs[r];

#pragma unroll
        for (int dt = 0; dt < 8; ++dt)
#pragma unroll
            for (int r = 0; r < 4; ++r) o[dt][r] *= sc[r];

        // per-wave P transpose through private LDS buffer (intra-wave RAW only)
#pragma unroll
        for (int h = 0; h < 2; ++h)
#pragma unroll
            for (int r = 0; r < 4; ++r)
                Pbuf[w][(lg * 4 + r) * 32 + h * 16 + lr] = f2bf(p[h][r]);

        bf16x8 pa = *(const bf16x8*)(&Pbuf[w][lr * 32 + lg * 8]);

#pragma unroll
        for (int dt = 0; dt < 8; ++dt) {
            bf16x8 vf = *(const bf16x8*)(Vb + (size_t)(dt * 16 + lr) * TT + kbase + lg * 8);
            o[dt] = __builtin_amdgcn_mfma_f32_16x16x32_bf16(pa, vf, o[dt], 0, 0, 0);
        }
    }

    // ---- block-level combine of 8 wave partials ----
#pragma unroll
    for (int dt = 0; dt < 8; ++dt)
#pragma unroll
        for (int r = 0; r < 4; ++r)
            Opart[w][lg * 4 + r][dt * 16 + lr] = o[dt][r];
    if (lr == 0) {
#pragma unroll
        for (int r = 0; r < 4; ++r) { Mp[w][lg * 4 + r] = m[r]; Lp[w][lg * 4 + r] = l[r]; }
    }
    __syncthreads();

    if (tid < 16) {
        float M = -INFINITY;
#pragma unroll
        for (int ww = 0; ww < 8; ++ww) M = fmaxf(M, Mp[ww][tid]);
        float L = 0.f;
#pragma unroll
        for (int ww = 0; ww < 8; ++ww) {
            float e = __expf(Mp[ww][tid] - M);   // Mp=-inf (idle wave) -> 0
            Esc[ww][tid] = e;
            L += Lp[ww][tid] * e;
        }
        Lfin[tid] = L;
    }
    __syncthreads();

    int row = tid >> 5, col = (tid & 31) * 4;
    float ax = 0.f, ay = 0.f, az = 0.f, aw = 0.f;
#pragma unroll
    for (int ww = 0; ww < 8; ++ww) {
        float e = Esc[ww][row];
        float4 v = *(const float4*)&Opart[ww][row][col];
        ax += v.x * e; ay += v.y * e; az += v.z * e; aw += v.w * e;
    }
    float inv = 1.f / Lfin[row];
    float4 res = { ax * inv, ay * inv, az * inv, aw * inv };
    *(float4*)(out + ((size_t)b * TT + r0 + row) * DD + col) = res;
}

extern "C" void kernel_launch(void* const* d_in, const int* in_sizes, int n_in,
                              void* d_out, int out_size, void* d_ws, size_t ws_size,
                              hipStream_t stream) {
    const float* x  = (const float*)d_in[0];
    const float* Wq = (const float*)d_in[1];
    const float* Wk = (const float*)d_in[2];
    const float* Wv = (const float*)d_in[3];
    float* out = (float*)d_out;

    char* ws = (char*)d_ws;
    short* Wall = (short*)ws;                              //   786,432 B
    short* Q    = (short*)(ws + 786432);                   // 4,194,304 B
    short* K    = (short*)(ws + 786432 + 4194304);
    short* Vt   = (short*)(ws + 786432 + 2 * 4194304);
    short* Xb   = (short*)(ws + 786432 + 3 * 4194304);     // 33,554,432 B
    const size_t need_bf = 786432 + 3ull * 4194304 + 33554432ull;

    prep_w<<<384, 256, 0, stream>>>(Wq, Wk, Wv, Wall);
    if (ws_size >= need_bf) {
        xconv<<<(16777216 / 8) / 256, 256, 0, stream>>>(x, Xb);
        qkv_gemm_bf<<<16384 / 64, 512, 0, stream>>>(Xb, Wall, Q, K, Vt);
    } else {
        qkv_gemm<<<16384 / 64, 512, 0, stream>>>(x, Wall, Q, K, Vt);
    }
    attn<<<BB * 128, 512, 0, stream>>>(Q, K, Vt, out);
}

// Round 6
// 132.612 us; speedup vs baseline: 1.3297x; 1.1612x over previous
//
#include <hip/hip_runtime.h>
#include <hip/hip_bf16.h>

#define TT 2048
#define CC 1024
#define DD 128
#define BB 8

typedef __attribute__((ext_vector_type(8))) short bf16x8;
typedef __attribute__((ext_vector_type(4))) float f32x4;
typedef __attribute__((ext_vector_type(16))) float f32x16;
typedef __attribute__((ext_vector_type(4))) short short4v;

__device__ inline short f2bf(float f) {
    union { float f; unsigned u; } v; v.f = f;
    unsigned r = v.u + 0x7FFFu + ((v.u >> 16) & 1u);   // RNE
    return (short)(r >> 16);
}

__device__ inline unsigned pack2(float lo, float hi) {  // two f32 -> packed bf16x2 word
    return (unsigned)(unsigned short)f2bf(lo) | ((unsigned)(unsigned short)f2bf(hi) << 16);
}

// ---------------- Kernel 1: pack Wq|Wk|Wv -> bf16 Wall[384][1024] ----------------
__global__ void prep_w(const float* __restrict__ Wq, const float* __restrict__ Wk,
                       const float* __restrict__ Wv, short* __restrict__ Wall) {
    int row = blockIdx.x;  // 0..383
    const float* src = row < 128 ? Wq + (size_t)row * CC
                     : row < 256 ? Wk + (size_t)(row - 128) * CC
                                 : Wv + (size_t)(row - 256) * CC;
    short* dst = Wall + (size_t)row * CC;
    for (int j = threadIdx.x; j < CC; j += 256) dst[j] = f2bf(src[j]);
}

// ---------------- Kernel 1b: X fp32 -> bf16, streaming ----------------
__global__ __launch_bounds__(256) void xconv(const float* __restrict__ X, short* __restrict__ Xb) {
    size_t i = ((size_t)blockIdx.x * 256 + threadIdx.x) * 8;
    float4 f0 = *(const float4*)(X + i);
    float4 f1 = *(const float4*)(X + i + 4);
    bf16x8 t;
    t[0] = f2bf(f0.x); t[1] = f2bf(f0.y); t[2] = f2bf(f0.z); t[3] = f2bf(f0.w);
    t[4] = f2bf(f1.x); t[5] = f2bf(f1.y); t[6] = f2bf(f1.z); t[7] = f2bf(f1.w);
    *(bf16x8*)(Xb + i) = t;
}

// ---------------- Kernel 2a: QKV projection GEMM from bf16 X ----------------
__global__ __launch_bounds__(512) void qkv_gemm_bf(const short* __restrict__ Xb,
                                                   const short* __restrict__ Wall,
                                                   short* __restrict__ Q,
                                                   short* __restrict__ K,
                                                   short* __restrict__ Vt) {
    int tid = threadIdx.x, lane = tid & 63, wid = tid >> 6;
    int wm = wid >> 2, wn = wid & 3;
    int m0 = blockIdx.x * 64 + wm * 32;
    int n0 = wn * 96;
    int lg = lane >> 4, lr = lane & 15;

    f32x4 acc[2][6] = {};

    for (int kb = 0; kb < CC; kb += 32) {
        int kf = kb + lg * 8;
        bf16x8 a[2], bfr[6];
#pragma unroll
        for (int mi = 0; mi < 2; ++mi)
            a[mi] = *(const bf16x8*)(Xb + (size_t)(m0 + mi * 16 + lr) * CC + kf);
#pragma unroll
        for (int nj = 0; nj < 6; ++nj)
            bfr[nj] = *(const bf16x8*)(Wall + (size_t)(n0 + nj * 16 + lr) * CC + kf);
#pragma unroll
        for (int mi = 0; mi < 2; ++mi)
#pragma unroll
            for (int nj = 0; nj < 6; ++nj)
                acc[mi][nj] = __builtin_amdgcn_mfma_f32_16x16x32_bf16(a[mi], bfr[nj], acc[mi][nj], 0, 0, 0);
    }

    int bidx = (blockIdx.x * 64) / TT;
#pragma unroll
    for (int mi = 0; mi < 2; ++mi) {
        int row = m0 + mi * 16 + lg * 4;
        int t = row - bidx * TT;
#pragma unroll
        for (int nj = 0; nj < 6; ++nj) {
            int col = n0 + nj * 16 + lr;
            if (col < 128) {
                short* dst = Q + ((size_t)bidx * TT + t) * DD + col;
#pragma unroll
                for (int r = 0; r < 4; ++r) dst[(size_t)r * DD] = f2bf(acc[mi][nj][r]);
            } else if (col < 256) {
                short* dst = K + ((size_t)bidx * TT + t) * DD + (col - 128);
#pragma unroll
                for (int r = 0; r < 4; ++r) dst[(size_t)r * DD] = f2bf(acc[mi][nj][r]);
            } else {
                short4v v4;
#pragma unroll
                for (int r = 0; r < 4; ++r) v4[r] = f2bf(acc[mi][nj][r]);
                *(short4v*)(Vt + ((size_t)bidx * DD + (col - 256)) * TT + t) = v4;
            }
        }
    }
}

// ---------------- Kernel 2b: fallback (fp32 X loads) ----------------
__global__ __launch_bounds__(512) void qkv_gemm(const float* __restrict__ X,
                                                const short* __restrict__ Wall,
                                                short* __restrict__ Q,
                                                short* __restrict__ K,
                                                short* __restrict__ Vt) {
    int tid = threadIdx.x, lane = tid & 63, wid = tid >> 6;
    int wm = wid >> 2, wn = wid & 3;
    int m0 = blockIdx.x * 64 + wm * 32;
    int n0 = wn * 96;
    int lg = lane >> 4, lr = lane & 15;

    f32x4 acc[2][6] = {};

    for (int kb = 0; kb < CC; kb += 32) {
        int kf = kb + lg * 8;
        bf16x8 a[2], bfr[6];
#pragma unroll
        for (int mi = 0; mi < 2; ++mi) {
            const float* p = X + (size_t)(m0 + mi * 16 + lr) * CC + kf;
            float4 f0 = *(const float4*)(p);
            float4 f1 = *(const float4*)(p + 4);
            bf16x8 t;
            t[0] = f2bf(f0.x); t[1] = f2bf(f0.y); t[2] = f2bf(f0.z); t[3] = f2bf(f0.w);
            t[4] = f2bf(f1.x); t[5] = f2bf(f1.y); t[6] = f2bf(f1.z); t[7] = f2bf(f1.w);
            a[mi] = t;
        }
#pragma unroll
        for (int nj = 0; nj < 6; ++nj)
            bfr[nj] = *(const bf16x8*)(Wall + (size_t)(n0 + nj * 16 + lr) * CC + kf);
#pragma unroll
        for (int mi = 0; mi < 2; ++mi)
#pragma unroll
            for (int nj = 0; nj < 6; ++nj)
                acc[mi][nj] = __builtin_amdgcn_mfma_f32_16x16x32_bf16(a[mi], bfr[nj], acc[mi][nj], 0, 0, 0);
    }

    int bidx = (blockIdx.x * 64) / TT;
#pragma unroll
    for (int mi = 0; mi < 2; ++mi) {
        int row = m0 + mi * 16 + lg * 4;
        int t = row - bidx * TT;
#pragma unroll
        for (int nj = 0; nj < 6; ++nj) {
            int col = n0 + nj * 16 + lr;
            if (col < 128) {
                short* dst = Q + ((size_t)bidx * TT + t) * DD + col;
#pragma unroll
                for (int r = 0; r < 4; ++r) dst[(size_t)r * DD] = f2bf(acc[mi][nj][r]);
            } else if (col < 256) {
                short* dst = K + ((size_t)bidx * TT + t) * DD + (col - 128);
#pragma unroll
                for (int r = 0; r < 4; ++r) dst[(size_t)r * DD] = f2bf(acc[mi][nj][r]);
            } else {
                short4v v4;
#pragma unroll
                for (int r = 0; r < 4; ++r) v4[r] = f2bf(acc[mi][nj][r]);
                *(short4v*)(Vt + ((size_t)bidx * DD + (col - 256)) * TT + t) = v4;
            }
        }
    }
}

// ---------------- Kernel 3: causal flash attention, 32x32 swapped-QK ----------------
// S^T = mfma(K,Q): lane (q,lg2) holds S[key kl(r)][q], kl(r)=(r&3)+8*(r>>2)+4*lg2.
// Packed P words per 16-key chunk: lo lanes hold key pairs (0,1),(2,3),(8,9),(10,11)
// in words 0..3; hi lanes (4,5),(6,7),(12,13),(14,15). PV B-frag word j needs keys
// (2j,2j+1) on lo lanes, (8+2j,8+2j+1) on hi lanes -> cross-half shfl_xor(32)+select.
// mb is the exp BASE (not the max): NaN-proof by construction (never -inf minus -inf).
#define PV_CHUNK(WS, H, CB) do {                                                   \
    unsigned a0 = WS[4*(H)+0], a1 = WS[4*(H)+1];                                   \
    unsigned b0 = WS[4*(H)+2], b1 = WS[4*(H)+3];                                   \
    unsigned xa0 = (unsigned)__shfl_xor((int)a0, 32, 64);                          \
    unsigned xa1 = (unsigned)__shfl_xor((int)a1, 32, 64);                          \
    unsigned xb0 = (unsigned)__shfl_xor((int)b0, 32, 64);                          \
    unsigned xb1 = (unsigned)__shfl_xor((int)b1, 32, 64);                          \
    union { unsigned u[4]; bf16x8 v; } pu;                                         \
    pu.u[0] = lg2 ? xb0 : a0;   /* lo:(0,1)   hi:(8,9)   */                        \
    pu.u[1] = lg2 ? xb1 : a1;   /* lo:(2,3)   hi:(10,11) */                        \
    pu.u[2] = lg2 ? b0  : xa0;  /* lo:(4,5)   hi:(12,13) */                        \
    pu.u[3] = lg2 ? b1  : xa1;  /* lo:(6,7)   hi:(14,15) */                        \
    const short* Vp = Vb + kbase + (CB)*16 + lg2*8;                                \
    _Pragma("unroll")                                                              \
    for (int dt = 0; dt < 4; ++dt) {                                               \
        bf16x8 vf = *(const bf16x8*)(Vp + (size_t)(dt*32 + q) * TT);               \
        acc[dt] = __builtin_amdgcn_mfma_f32_32x32x16_bf16(vf, pu.v, acc[dt], 0,0,0);\
    }                                                                              \
} while (0)

__global__ __launch_bounds__(256) void attn32(const short* __restrict__ Q,
                                              const short* __restrict__ K,
                                              const short* __restrict__ Vt,
                                              float* __restrict__ out) {
    __shared__ float slot[2][4][32][33];   // [slot][dtile][d-row][query], padded
    __shared__ float ml[2][2][32];

    int tid = threadIdx.x;
    int lane = tid & 63, w = tid >> 6;
    int q = lane & 31, lg2 = lane >> 5;
    int bid = blockIdx.x;
    int b = bid & 7;                        // batch striped across XCDs
    int qt = 63 - (bid >> 3);               // heavy q-tiles first
    int r0 = qt * 32;
    int qq = r0 + q;

    const short* Qb = Q + (size_t)b * TT * DD;
    const short* Kb = K + (size_t)b * TT * DD;
    const short* Vb = Vt + (size_t)b * DD * TT;

    bf16x8 qf[8];                           // B-frags: Q^T[k][query]
#pragma unroll
    for (int kc = 0; kc < 8; ++kc)
        qf[kc] = *(const bf16x8*)(Qb + (size_t)qq * DD + kc * 16 + lg2 * 8);

    f32x16 acc[4] = {};                     // O^T, 4 d-tiles of 32
    float mb = -INFINITY, l = 0.f;          // mb: exp base; l: sum relative to mb
    const float scale = 0.08838834764831845f;  // 128^-0.5
    int kend = r0 + 32;

    for (int kt = w; kt * 64 < kend; kt += 4) {
        int kbase = kt * 64;
        f32x16 s0 = {}, s1 = {};
        const short* Kp0 = Kb + (size_t)(kbase + q) * DD + lg2 * 8;
        const short* Kp1 = Kp0 + (size_t)32 * DD;
#pragma unroll
        for (int kc = 0; kc < 8; ++kc) {
            bf16x8 k0 = *(const bf16x8*)(Kp0 + kc * 16);
            bf16x8 k1 = *(const bf16x8*)(Kp1 + kc * 16);
            s0 = __builtin_amdgcn_mfma_f32_32x32x16_bf16(k0, qf[kc], s0, 0, 0, 0);
            s1 = __builtin_amdgcn_mfma_f32_32x32x16_bf16(k1, qf[kc], s1, 0, 0, 0);
        }

        if (kbase + 63 > r0) {              // masking needed (wave-uniform)
#pragma unroll
            for (int r = 0; r < 16; ++r) {
                int kl = (r & 3) + 8 * (r >> 2) + 4 * lg2;
                s0[r] = (kbase + kl > qq) ? -INFINITY : s0[r] * scale;
                s1[r] = (kbase + 32 + kl > qq) ? -INFINITY : s1[r] * scale;
            }
        } else {
#pragma unroll
            for (int r = 0; r < 16; ++r) { s0[r] *= scale; s1[r] *= scale; }
        }

        // per-query tile max: in-lane tree over 32 regs + half-pair exchange
        float tmx[16];
#pragma unroll
        for (int r = 0; r < 16; ++r) tmx[r] = fmaxf(s0[r], s1[r]);
#pragma unroll
        for (int st = 8; st; st >>= 1)
#pragma unroll
            for (int r = 0; r < 8; ++r) if (r < st) tmx[r] = fmaxf(tmx[r], tmx[r + st]);
        float pm = fmaxf(tmx[0], __shfl_xor(tmx[0], 32, 64));

        // defer-max rescale (T13), -inf-proof: mb stays the clamped exp base.
        if (__any(pm > mb + 8.f)) {
            float mn = fmaxf(mb, pm);
            float mc = (mn == -INFINITY) ? 0.f : mn;   // fully-masked corner
            float sc = __expf(mb - mc);                // mb=-inf -> 0 (acc,l are 0 anyway)
            mb = mc; l *= sc;
#pragma unroll
            for (int dt = 0; dt < 4; ++dt)
#pragma unroll
                for (int r = 0; r < 16; ++r) acc[dt][r] *= sc;
        }
        // here mb is finite; masked s=-inf -> exp(-inf - mb)=0; no-rescale case s-mb<=8

        // exp in place
#pragma unroll
        for (int r = 0; r < 16; ++r) { s0[r] = __expf(s0[r] - mb); s1[r] = __expf(s1[r] - mb); }

        // row-sum: in-lane tree + half-pair exchange
        float ts[16];
#pragma unroll
        for (int r = 0; r < 16; ++r) ts[r] = s0[r] + s1[r];
#pragma unroll
        for (int st = 8; st; st >>= 1)
#pragma unroll
            for (int r = 0; r < 8; ++r) if (r < st) ts[r] += ts[r + st];
        l += ts[0] + __shfl_xor(ts[0], 32, 64);

        // pack P -> bf16 word pairs (portable; compiler emits packs)
        unsigned w0[8], w1[8];
#pragma unroll
        for (int k2 = 0; k2 < 8; ++k2) {
            w0[k2] = pack2(s0[2 * k2], s0[2 * k2 + 1]);
            w1[k2] = pack2(s1[2 * k2], s1[2 * k2 + 1]);
        }

        // PV: 4 chunks of 16 keys
        PV_CHUNK(w0, 0, 0);
        PV_CHUNK(w0, 1, 1);
        PV_CHUNK(w1, 0, 2);
        PV_CHUNK(w1, 1, 3);
    }

    // ---- tree combine of 4 wave partials through LDS (m := mb, partial-base) ----
    if (w >= 2) {
        int s = w - 2;
#pragma unroll
        for (int dt = 0; dt < 4; ++dt)
#pragma unroll
            for (int r = 0; r < 16; ++r)
                slot[s][dt][(r & 3) + 8 * (r >> 2) + 4 * lg2][q] = acc[dt][r];
        if (lg2 == 0) { ml[s][0][q] = mb; ml[s][1][q] = l; }
    }
    __syncthreads();
    if (w < 2) {
        int s = w;
        float m2 = ml[s][0][q], l2 = ml[s][1][q];
        float M = fmaxf(mb, m2);
        float Mc = (M == -INFINITY) ? 0.f : M;
        float e1 = __expf(mb - Mc), e2 = __expf(m2 - Mc);
        mb = M; l = l * e1 + l2 * e2;
#pragma unroll
        for (int dt = 0; dt < 4; ++dt)
#pragma unroll
            for (int r = 0; r < 16; ++r)
                acc[dt][r] = acc[dt][r] * e1 + slot[s][dt][(r & 3) + 8 * (r >> 2) + 4 * lg2][q] * e2;
    }
    __syncthreads();
    if (w == 1) {
#pragma unroll
        for (int dt = 0; dt < 4; ++dt)
#pragma unroll
            for (int r = 0; r < 16; ++r)
                slot[0][dt][(r & 3) + 8 * (r >> 2) + 4 * lg2][q] = acc[dt][r];
        if (lg2 == 0) { ml[0][0][q] = mb; ml[0][1][q] = l; }
    }
    __syncthreads();
    if (w == 0) {
        float m2 = ml[0][0][q], l2 = ml[0][1][q];
        float M = fmaxf(mb, m2);
        float Mc = (M == -INFINITY) ? 0.f : M;
        float e1 = __expf(mb - Mc), e2 = __expf(m2 - Mc);
        l = l * e1 + l2 * e2;
        float inv = 1.f / l;
#pragma unroll
        for (int dt = 0; dt < 4; ++dt)
#pragma unroll
            for (int rq = 0; rq < 4; ++rq) {
                f32x4 o4;
#pragma unroll
                for (int j = 0; j < 4; ++j) {
                    int r = rq * 4 + j;
                    o4[j] = (acc[dt][r] * e1 + slot[0][dt][(r & 3) + 8 * rq + 4 * lg2][q] * e2) * inv;
                }
                *(f32x4*)(out + ((size_t)b * TT + qq) * DD + dt * 32 + rq * 8 + lg2 * 4) = o4;
            }
    }
}

extern "C" void kernel_launch(void* const* d_in, const int* in_sizes, int n_in,
                              void* d_out, int out_size, void* d_ws, size_t ws_size,
                              hipStream_t stream) {
    const float* x  = (const float*)d_in[0];
    const float* Wq = (const float*)d_in[1];
    const float* Wk = (const float*)d_in[2];
    const float* Wv = (const float*)d_in[3];
    float* out = (float*)d_out;

    char* ws = (char*)d_ws;
    short* Wall = (short*)ws;                              //   786,432 B
    short* Q    = (short*)(ws + 786432);                   // 4,194,304 B
    short* K    = (short*)(ws + 786432 + 4194304);
    short* Vt   = (short*)(ws + 786432 + 2 * 4194304);
    short* Xb   = (short*)(ws + 786432 + 3 * 4194304);     // 33,554,432 B
    const size_t need_bf = 786432 + 3ull * 4194304 + 33554432ull;

    prep_w<<<384, 256, 0, stream>>>(Wq, Wk, Wv, Wall);
    if (ws_size >= need_bf) {
        xconv<<<(16777216 / 8) / 256, 256, 0, stream>>>(x, Xb);
        qkv_gemm_bf<<<16384 / 64, 512, 0, stream>>>(Xb, Wall, Q, K, Vt);
    } else {
        qkv_gemm<<<16384 / 64, 512, 0, stream>>>(x, Wall, Q, K, Vt);
    }
    attn32<<<BB * 64, 256, 0, stream>>>(Q, K, Vt, out);
}

// Round 7
// 93.645 us; speedup vs baseline: 1.8830x; 1.4161x over previous
//
#include <hip/hip_runtime.h>
#include <hip/hip_bf16.h>

#define TT 2048
#define CC 1024
#define DD 128
#define BB 8
#define BK 32
#define NSTEP (CC / BK)   // 32 K-steps

typedef __attribute__((ext_vector_type(8))) short bf16x8;
typedef __attribute__((ext_vector_type(4))) float f32x4;
typedef __attribute__((ext_vector_type(16))) float f32x16;
typedef __attribute__((ext_vector_type(4))) short short4v;

__device__ inline short f2bf(float f) {
    union { float f; unsigned u; } v; v.f = f;
    unsigned r = v.u + 0x7FFFu + ((v.u >> 16) & 1u);   // RNE
    return (short)(r >> 16);
}

__device__ inline unsigned pack2(float lo, float hi) {  // two f32 -> packed bf16x2 word
    return (unsigned)(unsigned short)f2bf(lo) | ((unsigned)(unsigned short)f2bf(hi) << 16);
}

// async global->LDS, 16B per lane (guide §5 / Common-mistake #1)
#define GLOAD16(gp, lp) __builtin_amdgcn_global_load_lds(                       \
    (const __attribute__((address_space(1))) unsigned int*)(const void*)(gp),   \
    (__attribute__((address_space(3))) unsigned int*)(void*)(lp), 16, 0, 0)

// ---------------- Kernel 1: pack Wq|Wk|Wv -> bf16 Wall[384][1024] ----------------
__global__ void prep_w(const float* __restrict__ Wq, const float* __restrict__ Wk,
                       const float* __restrict__ Wv, short* __restrict__ Wall) {
    int row = blockIdx.x;  // 0..383
    const float* src = row < 128 ? Wq + (size_t)row * CC
                     : row < 256 ? Wk + (size_t)(row - 128) * CC
                                 : Wv + (size_t)(row - 256) * CC;
    short* dst = Wall + (size_t)row * CC;
    for (int j = threadIdx.x; j < CC; j += 256) dst[j] = f2bf(src[j]);
}

// ---------------- Kernel 1b: X fp32 -> bf16, streaming ----------------
__global__ __launch_bounds__(256) void xconv(const float* __restrict__ X, short* __restrict__ Xb) {
    size_t i = ((size_t)blockIdx.x * 256 + threadIdx.x) * 8;
    float4 f0 = *(const float4*)(X + i);
    float4 f1 = *(const float4*)(X + i + 4);
    bf16x8 t;
    t[0] = f2bf(f0.x); t[1] = f2bf(f0.y); t[2] = f2bf(f0.z); t[3] = f2bf(f0.w);
    t[4] = f2bf(f1.x); t[5] = f2bf(f1.y); t[6] = f2bf(f1.z); t[7] = f2bf(f1.w);
    *(bf16x8*)(Xb + i) = t;
}

// ---------------- Kernel 2: QKV GEMM, LDS-staged (m97-style) ----------------
// C[16384][384] = Xb · Wall^T. Tile 64(M)x128(N), BK=32, 4 waves (wave = 32x64).
// grid = (256 row-tiles, 3 col-tiles); col-tile 0->Q, 1->K, 2->Vt (transposed).
// LDS per buffer: A 64x32 bf16 (4KB) + B 128x32 bf16 (8KB); double-buffered.
__global__ __launch_bounds__(256) void qkv_gemm_lds(const short* __restrict__ Xb,
                                                    const short* __restrict__ Wall,
                                                    short* __restrict__ Q,
                                                    short* __restrict__ K,
                                                    short* __restrict__ Vt) {
    __shared__ char lds[2 * 12288];
    int tid = threadIdx.x, lane = tid & 63, wid = tid >> 6;
    int wm = wid >> 1, wn = wid & 1;          // 2x2 wave grid
    int lg = lane >> 4, lr = lane & 15;
    int m0 = blockIdx.x * 64;
    int n0 = blockIdx.y * 128;

    int arow = tid >> 2, achk = (tid & 3) * 8;         // staging coords
    const short* gA  = Xb   + (size_t)(m0 + arow) * CC + achk;
    const short* gB0 = Wall + (size_t)(n0 + arow) * CC + achk;
    const short* gB1 = gB0 + (size_t)64 * CC;

    f32x4 acc[2][4] = {};

#define STAGE(kb, buf) do {                                                     \
        char* base_ = lds + (buf) * 12288;                                      \
        GLOAD16(gA  + (kb), base_ + tid * 16);                                  \
        GLOAD16(gB0 + (kb), base_ + 4096 + tid * 16);                           \
        GLOAD16(gB1 + (kb), base_ + 8192 + tid * 16);                           \
    } while (0)

#define KSTEP(buf) do {                                                         \
        const char* base_ = lds + (buf) * 12288;                                \
        bf16x8 a_[2], b_[4];                                                    \
        _Pragma("unroll")                                                       \
        for (int mi = 0; mi < 2; ++mi)                                          \
            a_[mi] = *(const bf16x8*)(base_ + (wm*32 + mi*16 + lr) * 64 + lg*16);\
        _Pragma("unroll")                                                       \
        for (int nj = 0; nj < 4; ++nj)                                          \
            b_[nj] = *(const bf16x8*)(base_ + 4096 + (wn*64 + nj*16 + lr) * 64 + lg*16);\
        _Pragma("unroll")                                                       \
        for (int mi = 0; mi < 2; ++mi)                                          \
            _Pragma("unroll")                                                   \
            for (int nj = 0; nj < 4; ++nj)                                      \
                acc[mi][nj] = __builtin_amdgcn_mfma_f32_16x16x32_bf16(a_[mi], b_[nj], acc[mi][nj], 0, 0, 0);\
    } while (0)

    STAGE(0, 0);
#pragma unroll 2
    for (int t = 0; t < NSTEP; ++t) {
        __syncthreads();                       // staged tile t visible; reads of t-1 done
        if (t + 1 < NSTEP) STAGE((t + 1) * BK, (t + 1) & 1);
        KSTEP(t & 1);
    }
#undef STAGE
#undef KSTEP

    int bidx = m0 >> 11;                       // batch (64 | 2048)
    int nt = blockIdx.y;
#pragma unroll
    for (int mi = 0; mi < 2; ++mi) {
        int row = m0 + wm * 32 + mi * 16 + lg * 4;
        int t = row - bidx * TT;
#pragma unroll
        for (int nj = 0; nj < 4; ++nj) {
            int col = wn * 64 + nj * 16 + lr;  // 0..127 within this output
            if (nt == 0) {
                short* dst = Q + ((size_t)bidx * TT + t) * DD + col;
#pragma unroll
                for (int r = 0; r < 4; ++r) dst[(size_t)r * DD] = f2bf(acc[mi][nj][r]);
            } else if (nt == 1) {
                short* dst = K + ((size_t)bidx * TT + t) * DD + col;
#pragma unroll
                for (int r = 0; r < 4; ++r) dst[(size_t)r * DD] = f2bf(acc[mi][nj][r]);
            } else {
                short4v v4;
#pragma unroll
                for (int r = 0; r < 4; ++r) v4[r] = f2bf(acc[mi][nj][r]);
                *(short4v*)(Vt + ((size_t)bidx * DD + col) * TT + t) = v4;
            }
        }
    }
}

// ---------------- Kernel 2b: fallback (fp32 X, direct loads) ----------------
__global__ __launch_bounds__(512) void qkv_gemm(const float* __restrict__ X,
                                                const short* __restrict__ Wall,
                                                short* __restrict__ Q,
                                                short* __restrict__ K,
                                                short* __restrict__ Vt) {
    int tid = threadIdx.x, lane = tid & 63, wid = tid >> 6;
    int wm = wid >> 2, wn = wid & 3;
    int m0 = blockIdx.x * 64 + wm * 32;
    int n0 = wn * 96;
    int lg = lane >> 4, lr = lane & 15;

    f32x4 acc[2][6] = {};

    for (int kb = 0; kb < CC; kb += 32) {
        int kf = kb + lg * 8;
        bf16x8 a[2], bfr[6];
#pragma unroll
        for (int mi = 0; mi < 2; ++mi) {
            const float* p = X + (size_t)(m0 + mi * 16 + lr) * CC + kf;
            float4 f0 = *(const float4*)(p);
            float4 f1 = *(const float4*)(p + 4);
            bf16x8 t;
            t[0] = f2bf(f0.x); t[1] = f2bf(f0.y); t[2] = f2bf(f0.z); t[3] = f2bf(f0.w);
            t[4] = f2bf(f1.x); t[5] = f2bf(f1.y); t[6] = f2bf(f1.z); t[7] = f2bf(f1.w);
            a[mi] = t;
        }
#pragma unroll
        for (int nj = 0; nj < 6; ++nj)
            bfr[nj] = *(const bf16x8*)(Wall + (size_t)(n0 + nj * 16 + lr) * CC + kf);
#pragma unroll
        for (int mi = 0; mi < 2; ++mi)
#pragma unroll
            for (int nj = 0; nj < 6; ++nj)
                acc[mi][nj] = __builtin_amdgcn_mfma_f32_16x16x32_bf16(a[mi], bfr[nj], acc[mi][nj], 0, 0, 0);
    }

    int bidx = (blockIdx.x * 64) / TT;
#pragma unroll
    for (int mi = 0; mi < 2; ++mi) {
        int row = m0 + mi * 16 + lg * 4;
        int t = row - bidx * TT;
#pragma unroll
        for (int nj = 0; nj < 6; ++nj) {
            int col = n0 + nj * 16 + lr;
            if (col < 128) {
                short* dst = Q + ((size_t)bidx * TT + t) * DD + col;
#pragma unroll
                for (int r = 0; r < 4; ++r) dst[(size_t)r * DD] = f2bf(acc[mi][nj][r]);
            } else if (col < 256) {
                short* dst = K + ((size_t)bidx * TT + t) * DD + (col - 128);
#pragma unroll
                for (int r = 0; r < 4; ++r) dst[(size_t)r * DD] = f2bf(acc[mi][nj][r]);
            } else {
                short4v v4;
#pragma unroll
                for (int r = 0; r < 4; ++r) v4[r] = f2bf(acc[mi][nj][r]);
                *(short4v*)(Vt + ((size_t)bidx * DD + (col - 256)) * TT + t) = v4;
            }
        }
    }
}

// ---------------- Kernel 3: causal flash attention, 32x32 swapped-QK ----------------
// (unchanged from round-6 verified kernel)
#define PV_CHUNK(WS, H, CB) do {                                                   \
    unsigned a0 = WS[4*(H)+0], a1 = WS[4*(H)+1];                                   \
    unsigned b0 = WS[4*(H)+2], b1 = WS[4*(H)+3];                                   \
    unsigned xa0 = (unsigned)__shfl_xor((int)a0, 32, 64);                          \
    unsigned xa1 = (unsigned)__shfl_xor((int)a1, 32, 64);                          \
    unsigned xb0 = (unsigned)__shfl_xor((int)b0, 32, 64);                          \
    unsigned xb1 = (unsigned)__shfl_xor((int)b1, 32, 64);                          \
    union { unsigned u[4]; bf16x8 v; } pu;                                         \
    pu.u[0] = lg2 ? xb0 : a0;   /* lo:(0,1)   hi:(8,9)   */                        \
    pu.u[1] = lg2 ? xb1 : a1;   /* lo:(2,3)   hi:(10,11) */                        \
    pu.u[2] = lg2 ? b0  : xa0;  /* lo:(4,5)   hi:(12,13) */                        \
    pu.u[3] = lg2 ? b1  : xa1;  /* lo:(6,7)   hi:(14,15) */                        \
    const short* Vp = Vb + kbase + (CB)*16 + lg2*8;                                \
    _Pragma("unroll")                                                              \
    for (int dt = 0; dt < 4; ++dt) {                                               \
        bf16x8 vf = *(const bf16x8*)(Vp + (size_t)(dt*32 + q) * TT);               \
        acc[dt] = __builtin_amdgcn_mfma_f32_32x32x16_bf16(vf, pu.v, acc[dt], 0,0,0);\
    }                                                                              \
} while (0)

__global__ __launch_bounds__(256) void attn32(const short* __restrict__ Q,
                                              const short* __restrict__ K,
                                              const short* __restrict__ Vt,
                                              float* __restrict__ out) {
    __shared__ float slot[2][4][32][33];
    __shared__ float ml[2][2][32];

    int tid = threadIdx.x;
    int lane = tid & 63, w = tid >> 6;
    int q = lane & 31, lg2 = lane >> 5;
    int bid = blockIdx.x;
    int b = bid & 7;
    int qt = 63 - (bid >> 3);
    int r0 = qt * 32;
    int qq = r0 + q;

    const short* Qb = Q + (size_t)b * TT * DD;
    const short* Kb = K + (size_t)b * TT * DD;
    const short* Vb = Vt + (size_t)b * DD * TT;

    bf16x8 qf[8];
#pragma unroll
    for (int kc = 0; kc < 8; ++kc)
        qf[kc] = *(const bf16x8*)(Qb + (size_t)qq * DD + kc * 16 + lg2 * 8);

    f32x16 acc[4] = {};
    float mb = -INFINITY, l = 0.f;
    const float scale = 0.08838834764831845f;
    int kend = r0 + 32;

    for (int kt = w; kt * 64 < kend; kt += 4) {
        int kbase = kt * 64;
        f32x16 s0 = {}, s1 = {};
        const short* Kp0 = Kb + (size_t)(kbase + q) * DD + lg2 * 8;
        const short* Kp1 = Kp0 + (size_t)32 * DD;
#pragma unroll
        for (int kc = 0; kc < 8; ++kc) {
            bf16x8 k0 = *(const bf16x8*)(Kp0 + kc * 16);
            bf16x8 k1 = *(const bf16x8*)(Kp1 + kc * 16);
            s0 = __builtin_amdgcn_mfma_f32_32x32x16_bf16(k0, qf[kc], s0, 0, 0, 0);
            s1 = __builtin_amdgcn_mfma_f32_32x32x16_bf16(k1, qf[kc], s1, 0, 0, 0);
        }

        if (kbase + 63 > r0) {
#pragma unroll
            for (int r = 0; r < 16; ++r) {
                int kl = (r & 3) + 8 * (r >> 2) + 4 * lg2;
                s0[r] = (kbase + kl > qq) ? -INFINITY : s0[r] * scale;
                s1[r] = (kbase + 32 + kl > qq) ? -INFINITY : s1[r] * scale;
            }
        } else {
#pragma unroll
            for (int r = 0; r < 16; ++r) { s0[r] *= scale; s1[r] *= scale; }
        }

        float tmx[16];
#pragma unroll
        for (int r = 0; r < 16; ++r) tmx[r] = fmaxf(s0[r], s1[r]);
#pragma unroll
        for (int st = 8; st; st >>= 1)
#pragma unroll
            for (int r = 0; r < 8; ++r) if (r < st) tmx[r] = fmaxf(tmx[r], tmx[r + st]);
        float pm = fmaxf(tmx[0], __shfl_xor(tmx[0], 32, 64));

        if (__any(pm > mb + 8.f)) {
            float mn = fmaxf(mb, pm);
            float mc = (mn == -INFINITY) ? 0.f : mn;
            float sc = __expf(mb - mc);
            mb = mc; l *= sc;
#pragma unroll
            for (int dt = 0; dt < 4; ++dt)
#pragma unroll
                for (int r = 0; r < 16; ++r) acc[dt][r] *= sc;
        }

#pragma unroll
        for (int r = 0; r < 16; ++r) { s0[r] = __expf(s0[r] - mb); s1[r] = __expf(s1[r] - mb); }

        float ts[16];
#pragma unroll
        for (int r = 0; r < 16; ++r) ts[r] = s0[r] + s1[r];
#pragma unroll
        for (int st = 8; st; st >>= 1)
#pragma unroll
            for (int r = 0; r < 8; ++r) if (r < st) ts[r] += ts[r + st];
        l += ts[0] + __shfl_xor(ts[0], 32, 64);

        unsigned w0[8], w1[8];
#pragma unroll
        for (int k2 = 0; k2 < 8; ++k2) {
            w0[k2] = pack2(s0[2 * k2], s0[2 * k2 + 1]);
            w1[k2] = pack2(s1[2 * k2], s1[2 * k2 + 1]);
        }

        PV_CHUNK(w0, 0, 0);
        PV_CHUNK(w0, 1, 1);
        PV_CHUNK(w1, 0, 2);
        PV_CHUNK(w1, 1, 3);
    }

    if (w >= 2) {
        int s = w - 2;
#pragma unroll
        for (int dt = 0; dt < 4; ++dt)
#pragma unroll
            for (int r = 0; r < 16; ++r)
                slot[s][dt][(r & 3) + 8 * (r >> 2) + 4 * lg2][q] = acc[dt][r];
        if (lg2 == 0) { ml[s][0][q] = mb; ml[s][1][q] = l; }
    }
    __syncthreads();
    if (w < 2) {
        int s = w;
        float m2 = ml[s][0][q], l2 = ml[s][1][q];
        float M = fmaxf(mb, m2);
        float Mc = (M == -INFINITY) ? 0.f : M;
        float e1 = __expf(mb - Mc), e2 = __expf(m2 - Mc);
        mb = M; l = l * e1 + l2 * e2;
#pragma unroll
        for (int dt = 0; dt < 4; ++dt)
#pragma unroll
            for (int r = 0; r < 16; ++r)
                acc[dt][r] = acc[dt][r] * e1 + slot[s][dt][(r & 3) + 8 * (r >> 2) + 4 * lg2][q] * e2;
    }
    __syncthreads();
    if (w == 1) {
#pragma unroll
        for (int dt = 0; dt < 4; ++dt)
#pragma unroll
            for (int r = 0; r < 16; ++r)
                slot[0][dt][(r & 3) + 8 * (r >> 2) + 4 * lg2][q] = acc[dt][r];
        if (lg2 == 0) { ml[0][0][q] = mb; ml[0][1][q] = l; }
    }
    __syncthreads();
    if (w == 0) {
        float m2 = ml[0][0][q], l2 = ml[0][1][q];
        float M = fmaxf(mb, m2);
        float Mc = (M == -INFINITY) ? 0.f : M;
        float e1 = __expf(mb - Mc), e2 = __expf(m2 - Mc);
        l = l * e1 + l2 * e2;
        float inv = 1.f / l;
#pragma unroll
        for (int dt = 0; dt < 4; ++dt)
#pragma unroll
            for (int rq = 0; rq < 4; ++rq) {
                f32x4 o4;
#pragma unroll
                for (int j = 0; j < 4; ++j) {
                    int r = rq * 4 + j;
                    o4[j] = (acc[dt][r] * e1 + slot[0][dt][(r & 3) + 8 * rq + 4 * lg2][q] * e2) * inv;
                }
                *(f32x4*)(out + ((size_t)b * TT + qq) * DD + dt * 32 + rq * 8 + lg2 * 4) = o4;
            }
    }
}

extern "C" void kernel_launch(void* const* d_in, const int* in_sizes, int n_in,
                              void* d_out, int out_size, void* d_ws, size_t ws_size,
                              hipStream_t stream) {
    const float* x  = (const float*)d_in[0];
    const float* Wq = (const float*)d_in[1];
    const float* Wk = (const float*)d_in[2];
    const float* Wv = (const float*)d_in[3];
    float* out = (float*)d_out;

    char* ws = (char*)d_ws;
    short* Wall = (short*)ws;                              //   786,432 B
    short* Q    = (short*)(ws + 786432);                   // 4,194,304 B
    short* K    = (short*)(ws + 786432 + 4194304);
    short* Vt   = (short*)(ws + 786432 + 2 * 4194304);
    short* Xb   = (short*)(ws + 786432 + 3 * 4194304);     // 33,554,432 B
    const size_t need_bf = 786432 + 3ull * 4194304 + 33554432ull;

    prep_w<<<384, 256, 0, stream>>>(Wq, Wk, Wv, Wall);
    if (ws_size >= need_bf) {
        xconv<<<(16777216 / 8) / 256, 256, 0, stream>>>(x, Xb);
        qkv_gemm_lds<<<dim3(256, 3), 256, 0, stream>>>(Xb, Wall, Q, K, Vt);
    } else {
        qkv_gemm<<<16384 / 64, 512, 0, stream>>>(x, Wall, Q, K, Vt);
    }
    attn32<<<BB * 64, 256, 0, stream>>>(Q, K, Vt, out);
}